// Round 8
// baseline (331.194 us; speedup 1.0000x reference)
//
#include <hip/hip_runtime.h>
#include <stdint.h>
#include <math.h>

#define NH 16
#define DM 1024
#define SEQ 2048
#define DH 64
#define NB 4
// -1e9 premultiplied by log2(e): masked score -> exp2(-1.44e9) == 0
#define NEG2 (-1.4426950408889634e9f)
// (1/8) * log2(e)
#define SCL2 (0.18033688011112042f)

typedef __attribute__((ext_vector_type(8))) short bf16x8;
typedef __attribute__((ext_vector_type(4))) short bf16x4;
typedef __attribute__((ext_vector_type(4))) float f32x4;
typedef unsigned short u16;
typedef uint32_t u32;

__device__ __forceinline__ u16 f2bf(float f) {     // RNE
    union { float f; u32 i; } c; c.f = f;
    u32 r = c.i + 0x7fffu + ((c.i >> 16) & 1u);
    return (u16)(r >> 16);
}
// pack two f32 -> bf16x2 (round-half-up; inputs are exp() results, finite >=0)
// v_perm_b32 path: 3 VALU ops (2 add + 1 perm) vs 5; BIT-IDENTICAL result
// (both take high16 of x+0x8000).
__device__ __forceinline__ u32 packbf(float lo, float hi) {
    union { float f; u32 i; } a, b; a.f = lo; b.f = hi;
    u32 al = a.i + 0x8000u, bh = b.i + 0x8000u;
#if __has_builtin(__builtin_amdgcn_perm)
    // D.b0=lo.b2 D.b1=lo.b3 D.b2=hi.b2 D.b3=hi.b3 ; {S0=hi,S1=lo} sel 0x07060302
    return __builtin_amdgcn_perm(bh, al, 0x07060302u);
#else
    return (al >> 16) | (bh & 0xFFFF0000u);
#endif
}

__device__ __forceinline__ float fexp2(float x) {
#if __has_builtin(__builtin_amdgcn_exp2f)
    return __builtin_amdgcn_exp2f(x);
#else
    return exp2f(x);
#endif
}

__device__ __forceinline__ f32x4 pv_mfma(bf16x4 a, bf16x4 b, f32x4 c) {
#if __has_builtin(__builtin_amdgcn_mfma_f32_16x16x16bf16_1k)
    return __builtin_amdgcn_mfma_f32_16x16x16bf16_1k(a, b, c, 0, 0, 0);
#else
    f32x4 d;
    asm volatile("s_nop 1\n\t"
                 "v_mfma_f32_16x16x16_bf16 %0, %1, %2, %3\n\t"
                 "s_nop 7\n\t"
                 "s_nop 7"
                 : "=v"(d) : "v"(a), "v"(b), "v"(c));
    return d;
#endif
}

// async global->LDS, 16B per lane. LDS dest = wave-uniform base + lane*16.
__device__ __forceinline__ void gl_lds16(const u16* g, u16* l) {
#if __has_builtin(__builtin_amdgcn_global_load_lds)
    __builtin_amdgcn_global_load_lds(
        (const __attribute__((address_space(1))) void*)g,
        (__attribute__((address_space(3))) void*)l, 16, 0, 0);
#else
    *(uint4*)(l + (threadIdx.x & 63) * 8) = *(const uint4*)(g);
#endif
}

// f32 -> bf16 elementwise (fallback path only)
__global__ __launch_bounds__(256) void cvt_kernel(const float* __restrict__ src,
                                                  u16* __restrict__ dst, int n4) {
    int i = blockIdx.x * 256 + threadIdx.x;
    if (i >= n4) return;
    float4 v = ((const float4*)src)[i];
    ushort4 o = { f2bf(v.x), f2bf(v.y), f2bf(v.z), f2bf(v.w) };
    ((ushort4*)dst)[i] = o;
}

// fused prep: convert Wq,Wk,Wv (blocks 0..3071), build mask floats
// (3072..3103), and (full path) convert Q,K,V inputs (3104..27679).
// Fallback path launches only 3104 blocks (qxb/kxb/vxb may be null).
__global__ __launch_bounds__(256) void prep_kernel(
    const float* __restrict__ Wq, const float* __restrict__ Wk,
    const float* __restrict__ Wv, const int* __restrict__ mask,
    const float* __restrict__ Q, const float* __restrict__ K,
    const float* __restrict__ V,
    u16* __restrict__ wqb, u16* __restrict__ wkb, u16* __restrict__ wvb,
    float* __restrict__ mf,
    u16* __restrict__ qxb, u16* __restrict__ kxb, u16* __restrict__ vxb) {
    const int bid = blockIdx.x;
    if (bid < 3072) {
        const float* src = (bid < 1024) ? Wq : (bid < 2048) ? Wk : Wv;
        u16* dst = (bid < 1024) ? wqb : (bid < 2048) ? wkb : wvb;
        int i = (bid & 1023) * 256 + threadIdx.x;
        float4 v = ((const float4*)src)[i];
        ushort4 o = { f2bf(v.x), f2bf(v.y), f2bf(v.z), f2bf(v.w) };
        ((ushort4*)dst)[i] = o;
    } else if (bid < 3104) {
        int i = (bid - 3072) * 256 + threadIdx.x;   // 32 blocks * 256 = 8192
        mf[i] = mask[i] ? 0.0f : NEG2;
    } else {
        const int r = bid - 3104;                   // 0..24575
        const float* src = (r < 8192) ? Q : (r < 16384) ? K : V;
        u16* dst = (r < 8192) ? qxb : (r < 16384) ? kxb : vxb;
        int i = (r & 8191) * 256 + threadIdx.x;
        float4 v = ((const float4*)src)[i];
        ushort4 o = { f2bf(v.x), f2bf(v.y), f2bf(v.z), f2bf(v.w) };
        ((ushort4*)dst)[i] = o;
    }
}

// MERGED m97-style projection (full path): grid (8,192) = 1536 blocks =
// 6 blocks/CU of work, BK=32, 32KB LDS dbuf -> 4 resident blocks/CU.
// FROZEN since round 7 (~85us, ~600 TF).
__global__ __launch_bounds__(256, 4) void projm_kernel(
    const u16* __restrict__ qxb, const u16* __restrict__ kxb,
    const u16* __restrict__ vxb,
    const u16* __restrict__ wqb, const u16* __restrict__ wkb,
    const u16* __restrict__ wvb,
    const float* __restrict__ bq, const float* __restrict__ bv,
    u16* __restrict__ qo, u16* __restrict__ ko, u16* __restrict__ vo)
{
    __shared__ __align__(16) u16 sbuf[2][8192];   // [A 128x32 | B 128x32] = 16KB/buf
    const int p   = blockIdx.y * 8 + blockIdx.x;  // physical linear, x fastest
    const int xcd = p & 7;
    const int i8  = p >> 3;                       // 0..191
    const int ly  = xcd * 24 + (i8 >> 3);         // logical m-panel 0..191
    const int lx  = i8 & 7;                       // logical n-tile 0..7

    const int which = ly >> 6;                    // 0=Q 1=K 2=V
    const u16* X  = (which == 0) ? qxb : (which == 1) ? kxb : vxb;
    const u16* W  = (which == 0) ? wqb : (which == 1) ? wkb : wvb;
    const float* bias = (which == 0) ? bq : (which == 2) ? bv : nullptr;
    u16* out = (which == 0) ? qo : (which == 1) ? ko : vo;
    const int vt = (which == 2);

    const int tid  = threadIdx.x;
    const int lane = tid & 63;
    const int wave = tid >> 6;
    const int row  = lane & 15;
    const int quad = lane >> 4;
    const int n0 = lx * 128;
    const int m0 = (ly & 63) * 128;
    const int wm = (wave & 1) * 64;
    const int wn = (wave >> 1) * 64;

    const int r0 = wave * 16 + (lane >> 2);
    const int c0 = (lane & 3) ^ ((r0 >> 1) & 3);
    const u16* xg0 = X + (size_t)(m0 + r0) * DM + c0 * 8;
    const u16* xg1 = xg0 + (size_t)64 * DM;
    const u16* wg0 = W + (size_t)(n0 + r0) * DM + c0 * 8;
    const u16* wg1 = wg0 + (size_t)64 * DM;
    const int la0 = wave * 512;                   // wave-uniform base (u16)

    const int rsw = (quad ^ ((row >> 1) & 3)) * 8;  // read-side swizzle (0-conflict)

#define STAGE(bsel, kt) do {                         \
        u16* ab = &sbuf[bsel][la0];                  \
        gl_lds16(xg0 + (kt), ab);                    \
        gl_lds16(xg1 + (kt), ab + 2048);             \
        gl_lds16(wg0 + (kt), ab + 4096);             \
        gl_lds16(wg1 + (kt), ab + 6144);             \
    } while (0)

    f32x4 acc[4][4] = {};
    STAGE(0, 0);
    for (int ki = 0; ki < 32; ++ki) {
        __syncthreads();                 // vmcnt(0)+lgkm drain: buf[ki&1] complete
        if (ki < 31) STAGE((ki + 1) & 1, (ki + 1) * 32);

        const u16* Ab = sbuf[ki & 1];
        const u16* Bb = Ab + 4096;
        bf16x8 af[4], bfr[4];
#pragma unroll
        for (int i = 0; i < 4; i++)
            af[i] = *(const bf16x8*)(Ab + (wm + i * 16 + row) * 32 + rsw);
#pragma unroll
        for (int j = 0; j < 4; j++)
            bfr[j] = *(const bf16x8*)(Bb + (wn + j * 16 + row) * 32 + rsw);
#pragma unroll
        for (int i = 0; i < 4; i++)
#pragma unroll
            for (int j = 0; j < 4; j++)
                acc[i][j] = __builtin_amdgcn_mfma_f32_16x16x32_bf16(af[i], bfr[j], acc[i][j], 0, 0, 0);
    }
#undef STAGE

    const int bidx = m0 >> 11;
#pragma unroll
    for (int j = 0; j < 4; j++) {
        const int n = n0 + wn + j * 16 + row;
        const int h = n >> 6;
        const int c = n & (DH - 1);
        const float bvv = bias ? bias[n] : 0.0f;
#pragma unroll
        for (int i = 0; i < 4; i++) {
            const int mbase = m0 + wm + i * 16 + quad * 4;
            const int s = mbase & (SEQ - 1);
            if (vt) {
                ushort4 o = { f2bf(acc[i][j][0] + bvv), f2bf(acc[i][j][1] + bvv),
                              f2bf(acc[i][j][2] + bvv), f2bf(acc[i][j][3] + bvv) };
                size_t idx = (((size_t)(bidx * NH + h) * 32 + (s >> 6)) * DH + c) * 64 + (s & 63);
                *(ushort4*)(out + idx) = o;
            } else {
#pragma unroll
                for (int r = 0; r < 4; r++)
                    out[(size_t)((bidx * NH + h) * SEQ + s + r) * DH + c] = f2bf(acc[i][j][r] + bvv);
            }
        }
    }
}

// Single projection (fallback path, byte-identical to round 6, BK=64).
__global__ __launch_bounds__(256, 2) void proj_kernel(
    const u16* __restrict__ X, const u16* __restrict__ W,
    const float* __restrict__ bias, u16* __restrict__ out, int vt)
{
    __shared__ __align__(16) u16 sbuf[2][16384];
    const int p   = blockIdx.y * 8 + blockIdx.x;
    const int xcd = p & 7;
    const int i8  = p >> 3;                       // 0..63
    const int ly  = xcd * 8 + (i8 >> 3);          // logical m-panel 0..63
    const int lx  = i8 & 7;                       // logical n-tile 0..7

    const int tid  = threadIdx.x;
    const int lane = tid & 63;
    const int wave = tid >> 6;
    const int row  = lane & 15;
    const int quad = lane >> 4;
    const int n0 = lx * 128;
    const int m0 = ly * 128;
    const int wm = (wave & 1) * 64;
    const int wn = (wave >> 1) * 64;

    const int r0 = wave * 16 + (lane >> 2);
    const int c0 = (lane & 3) ^ ((r0 >> 1) & 3);
    const u16* xg0 = X + (size_t)(m0 + r0) * DM + c0 * 8;
    const u16* xg1 = xg0 + (size_t)64 * DM;
    const u16* wg0 = W + (size_t)(n0 + r0) * DM + c0 * 8;
    const u16* wg1 = wg0 + (size_t)64 * DM;
    const int la0 = wave * 512;

    const int rsw = (quad ^ ((row >> 1) & 3)) * 8;

#define STAGE(bsel, kt) do {                                 \
        u16* ab = &sbuf[bsel][la0];                          \
        gl_lds16(xg0 + (kt),        ab);                     \
        gl_lds16(xg1 + (kt),        ab + 2048);              \
        gl_lds16(xg0 + (kt) + 32,   ab + 4096);              \
        gl_lds16(xg1 + (kt) + 32,   ab + 6144);              \
        gl_lds16(wg0 + (kt),        ab + 8192);              \
        gl_lds16(wg1 + (kt),        ab + 10240);             \
        gl_lds16(wg0 + (kt) + 32,   ab + 12288);             \
        gl_lds16(wg1 + (kt) + 32,   ab + 14336);             \
    } while (0)

    f32x4 acc[4][4] = {};
    STAGE(0, 0);
    for (int ki = 0; ki < 16; ++ki) {
        __syncthreads();
        if (ki < 15) STAGE((ki + 1) & 1, (ki + 1) * 64);

        const u16* buf = sbuf[ki & 1];
#pragma unroll
        for (int ks = 0; ks < 2; ++ks) {
            const u16* Ab = buf + ks * 4096;
            const u16* Bb = buf + 8192 + ks * 4096;
            bf16x8 af[4], bfr[4];
#pragma unroll
            for (int i = 0; i < 4; i++)
                af[i] = *(const bf16x8*)(Ab + (wm + i * 16 + row) * 32 + rsw);
#pragma unroll
            for (int j = 0; j < 4; j++)
                bfr[j] = *(const bf16x8*)(Bb + (wn + j * 16 + row) * 32 + rsw);
#pragma unroll
            for (int i = 0; i < 4; i++)
#pragma unroll
                for (int j = 0; j < 4; j++)
                    acc[i][j] = __builtin_amdgcn_mfma_f32_16x16x32_bf16(af[i], bfr[j], acc[i][j], 0, 0, 0);
        }
    }
#undef STAGE

    const int bidx = m0 >> 11;
#pragma unroll
    for (int j = 0; j < 4; j++) {
        const int n = n0 + wn + j * 16 + row;
        const int h = n >> 6;
        const int c = n & (DH - 1);
        const float bvv = bias ? bias[n] : 0.0f;
#pragma unroll
        for (int i = 0; i < 4; i++) {
            const int mbase = m0 + wm + i * 16 + quad * 4;
            const int s = mbase & (SEQ - 1);
            if (vt) {
                ushort4 o = { f2bf(acc[i][j][0] + bvv), f2bf(acc[i][j][1] + bvv),
                              f2bf(acc[i][j][2] + bvv), f2bf(acc[i][j][3] + bvv) };
                size_t idx = (((size_t)(bidx * NH + h) * 32 + (s >> 6)) * DH + c) * 64 + (s & 63);
                *(ushort4*)(out + idx) = o;
            } else {
#pragma unroll
                for (int r = 0; r < 4; r++)
                    out[(size_t)((bidx * NH + h) * SEQ + s + r) * DH + c] = f2bf(acc[i][j][r] + bvv);
            }
        }
    }
}

// Flash attention, transposed-S, no online max. Block = 4 waves x 32 q = 128 q.
// Round-7 structure + XCD remap (FETCH 143->25MB verified). This round:
//  (a) packbf via v_perm_b32 (3 VALU ops/pair vs 5, bit-identical)
//  (b) softmax-denominator quad-reduce deferred to epilogue (removes 4
//      cross-lane shuffles/tile from the softmax->PV critical path;
//      exact: sum of reduces == reduce of sums)
__global__ __launch_bounds__(256, 3) void attn_kernel(
    const u16* __restrict__ qws, const u16* __restrict__ kws,
    const u16* __restrict__ vws, const float* __restrict__ maskf,
    float* __restrict__ out)
{
    __shared__ __align__(16) u16 kbuf[2][64 * 72];   // 9216 B each
    __shared__ __align__(16) u16 vbuf[2][64 * 72];   // rows = dh, cols = key
    const int tid  = threadIdx.x;
    const int lane = tid & 63;
    const int wave = tid >> 6;
    const int row  = lane & 15;
    const int quad = lane >> 4;
    const int bid0 = blockIdx.x;
    const int bid  = ((bid0 & 7) << 7) | (bid0 >> 3);   // XCD-chunked, bijective
    const int qb = bid & 15;            // SEQ/128 = 16
    const int h  = (bid >> 4) & (NH - 1);
    const int b  = bid >> 8;
    const int q0 = qb * 128 + wave * 32;

    const u16* qbase = qws + (size_t)(b * NH + h) * SEQ * DH;
    const u16* kbase = kws + (size_t)(b * NH + h) * SEQ * DH;
    const u16* vtb   = vws + (size_t)(b * NH + h) * 32 * (DH * 64); // tile-blocked
    const float* mrow = maskf + b * SEQ;

    const int srow = tid >> 3;          // 0..31
    const int scol = (tid & 7) * 8;
    const u16* kgp = kbase + (size_t)srow * DH + scol;
    const int ldso = srow * 72 + scol;
    const int vldso = ldso;

    bf16x8 qf[2][2];
#pragma unroll
    for (int gi = 0; gi < 2; gi++) {
        qf[gi][0] = *(const bf16x8*)(qbase + (size_t)(q0 + gi * 16 + row) * DH + quad * 8);
        qf[gi][1] = *(const bf16x8*)(qbase + (size_t)(q0 + gi * 16 + row) * DH + 32 + quad * 8);
    }

    f32x4 O[2][4] = {};
    float lrun[2] = {0.0f, 0.0f};

    {
        uint4 k0 = *(const uint4*)(kgp);
        uint4 k1 = *(const uint4*)(kgp + (size_t)32 * DH);
        uint4 v0 = *(const uint4*)(vtb + tid * 8);
        uint4 v1 = *(const uint4*)(vtb + (tid + 256) * 8);
        *(uint4*)(&kbuf[0][ldso])            = k0;
        *(uint4*)(&kbuf[0][32 * 72 + ldso])  = k1;
        *(uint4*)(&vbuf[0][vldso])           = v0;
        *(uint4*)(&vbuf[0][32 * 72 + vldso]) = v1;
    }

    for (int it = 0; it < 32; ++it) {
        const int kt = it * 64;
        __syncthreads();
        float4 mk[4];
#pragma unroll
        for (int g = 0; g < 4; g++)
            mk[g] = *(const float4*)(mrow + kt + g * 16 + quad * 4);
        const int itn = (it == 31) ? 0 : it + 1;
        uint4 kr0 = *(const uint4*)(kgp + (size_t)itn * 64 * DH);
        uint4 kr1 = *(const uint4*)(kgp + (size_t)(itn * 64 + 32) * DH);
        uint4 vr0 = *(const uint4*)(vtb + (size_t)itn * 4096 + tid * 8);
        uint4 vr1 = *(const uint4*)(vtb + (size_t)itn * 4096 + (tid + 256) * 8);

        const u16* kb = kbuf[it & 1];
        f32x4 st[2][4] = {};
#pragma unroll
        for (int g = 0; g < 4; g++) {
#pragma unroll
            for (int ks = 0; ks < 2; ks++) {
                bf16x8 kf = *(const bf16x8*)(kb + (g * 16 + row) * 72 + ks * 32 + quad * 8);
                st[0][g] = __builtin_amdgcn_mfma_f32_16x16x32_bf16(kf, qf[0][ks], st[0][g], 0, 0, 0);
                st[1][g] = __builtin_amdgcn_mfma_f32_16x16x32_bf16(kf, qf[1][ks], st[1][g], 0, 0, 0);
            }
        }

        union { u32 u[2]; bf16x4 v; } pw[2][4];
#pragma unroll
        for (int gi = 0; gi < 2; gi++) {
            float lsum = 0.0f;
#pragma unroll
            for (int g = 0; g < 4; g++) {
                float p0 = fexp2(fmaf(st[gi][g][0], SCL2, mk[g].x));
                float p1 = fexp2(fmaf(st[gi][g][1], SCL2, mk[g].y));
                float p2 = fexp2(fmaf(st[gi][g][2], SCL2, mk[g].z));
                float p3 = fexp2(fmaf(st[gi][g][3], SCL2, mk[g].w));
                lsum += (p0 + p1) + (p2 + p3);
                pw[gi][g].u[0] = packbf(p0, p1);
                pw[gi][g].u[1] = packbf(p2, p3);
            }
            lrun[gi] += lsum;            // lane-partial; quad-reduce deferred
        }

        const u16* vb = vbuf[it & 1];
#pragma unroll
        for (int dg = 0; dg < 4; dg++) {
#pragma unroll
            for (int g = 0; g < 4; g++) {
                bf16x4 vfrag = *(const bf16x4*)(vb + (dg * 16 + row) * 72 + g * 16 + quad * 4);
                O[0][dg] = pv_mfma(vfrag, pw[0][g].v, O[0][dg]);
                O[1][dg] = pv_mfma(vfrag, pw[1][g].v, O[1][dg]);
            }
        }

        u16* nkb = kbuf[(it + 1) & 1];
        u16* nvb = vbuf[(it + 1) & 1];
        *(uint4*)(nkb + ldso)             = kr0;
        *(uint4*)(nkb + 32 * 72 + ldso)   = kr1;
        *(uint4*)(nvb + vldso)            = vr0;
        *(uint4*)(nvb + 32 * 72 + vldso)  = vr1;
    }

#pragma unroll
    for (int gi = 0; gi < 2; gi++) {
        // deferred cross-quad reduction of the softmax denominator
        lrun[gi] += __shfl_xor(lrun[gi], 16, 64);
        lrun[gi] += __shfl_xor(lrun[gi], 32, 64);
        const float rl = 1.0f / lrun[gi];
        const int q = q0 + gi * 16 + row;
#pragma unroll
        for (int dg = 0; dg < 4; dg++) {
            float4 o4 = { O[gi][dg][0] * rl, O[gi][dg][1] * rl,
                          O[gi][dg][2] * rl, O[gi][dg][3] * rl };
            *(float4*)(out + (size_t)(b * SEQ + q) * (NH * DH) + h * DH + dg * 16 + quad * 4) = o4;
        }
    }
}

extern "C" void kernel_launch(void* const* d_in, const int* in_sizes, int n_in,
                              void* d_out, int out_size, void* d_ws, size_t ws_size,
                              hipStream_t stream) {
    const float* Q    = (const float*)d_in[0];
    const float* K    = (const float*)d_in[1];
    const float* V    = (const float*)d_in[2];
    const int*   mask = (const int*)d_in[3];
    const float* Wq   = (const float*)d_in[4];
    const float* bq   = (const float*)d_in[5];
    const float* Wk   = (const float*)d_in[6];
    const float* Wv   = (const float*)d_in[7];
    const float* bv   = (const float*)d_in[8];
    float* out = (float*)d_out;

    const size_t XN = (size_t)NB * SEQ * DM;     // 8,388,608
    const size_t WN = (size_t)DM * DM;           // 1,048,576
    dim3 blk(256);

    const size_t need_full = (6 * XN + 3 * WN) * 2 + 32768;   // ~102 MiB

    if (ws_size >= need_full) {
        // ---- full path: 3 kernels total ----
        u16* ws   = (u16*)d_ws;
        u16* qxb  = ws;
        u16* kxb  = qxb + XN;
        u16* vxb  = kxb + XN;
        u16* wqb  = vxb + XN;
        u16* wkb  = wqb + WN;
        u16* wvb  = wkb + WN;
        u16* qws  = wvb + WN;
        u16* kws  = qws + XN;
        u16* vws  = kws + XN;
        float* maskf = (float*)(vws + XN);

        prep_kernel<<<3104 + 3 * 8192, blk, 0, stream>>>(
            Wq, Wk, Wv, mask, Q, K, V, wqb, wkb, wvb, maskf, qxb, kxb, vxb);

        projm_kernel<<<dim3(8, 192), blk, 0, stream>>>(
            qxb, kxb, vxb, wqb, wkb, wvb, bq, bv, qws, kws, vws);

        attn_kernel<<<dim3(NB * NH * (SEQ / 128)), blk, 0, stream>>>(
            qws, kws, vws, maskf, out);
    } else {
        // ---- fallback: round-6 sequence (73.5 MB layout) ----
        u16* ws   = (u16*)d_ws;
        u16* xbuf = ws;                           // reused for Q, K, V inputs
        u16* wqb  = ws + XN;
        u16* wkb  = wqb + WN;
        u16* wvb  = wkb + WN;
        u16* qws  = wvb + WN;
        u16* kws  = qws + XN;
        u16* vws  = kws + XN;
        float* maskf = (float*)(vws + XN);

        const int gX = (int)(XN / 4 / 256);      // 8192
        dim3 pgrid(DM / 128, NB * SEQ / 128);    // (8, 64) = 512 blocks

        prep_kernel<<<3104, blk, 0, stream>>>(
            Wq, Wk, Wv, mask, Q, K, V, wqb, wkb, wvb, maskf,
            nullptr, nullptr, nullptr);

        cvt_kernel<<<gX, blk, 0, stream>>>(K, xbuf, (int)(XN / 4));
        proj_kernel<<<pgrid, blk, 0, stream>>>(xbuf, wkb, nullptr, kws, 0);
        cvt_kernel<<<gX, blk, 0, stream>>>(V, xbuf, (int)(XN / 4));
        proj_kernel<<<pgrid, blk, 0, stream>>>(xbuf, wvb, bv, vws, 1);
        cvt_kernel<<<gX, blk, 0, stream>>>(Q, xbuf, (int)(XN / 4));
        proj_kernel<<<pgrid, blk, 0, stream>>>(xbuf, wqb, bq, qws, 0);

        attn_kernel<<<dim3(NB * NH * (SEQ / 128)), blk, 0, stream>>>(
            qws, kws, vws, maskf, out);
    }
}

// Round 9
// 327.232 us; speedup vs baseline: 1.0121x; 1.0121x over previous
//
#include <hip/hip_runtime.h>
#include <stdint.h>
#include <math.h>

#define NH 16
#define DM 1024
#define SEQ 2048
#define DH 64
#define NB 4
// -1e9 premultiplied by log2(e): masked score -> exp2(-1.44e9) == 0
#define NEG2 (-1.4426950408889634e9f)
// (1/8) * log2(e)
#define SCL2 (0.18033688011112042f)

typedef __attribute__((ext_vector_type(8))) short bf16x8;
typedef __attribute__((ext_vector_type(4))) short bf16x4;
typedef __attribute__((ext_vector_type(4))) float f32x4;
typedef unsigned short u16;
typedef uint32_t u32;

__device__ __forceinline__ u16 f2bf(float f) {     // RNE
    union { float f; u32 i; } c; c.f = f;
    u32 r = c.i + 0x7fffu + ((c.i >> 16) & 1u);
    return (u16)(r >> 16);
}
// pack two f32 -> bf16x2 (round-half-up; inputs are exp() results, finite >=0)
// Round-7-exact version: r8's v_perm variant + deferred lsum measured +5us
// (codegen perturbation; VALUBusy dropped as predicted but dur rose).
__device__ __forceinline__ u32 packbf(float lo, float hi) {
    union { float f; u32 i; } a, b; a.f = lo; b.f = hi;
    return ((a.i + 0x8000u) >> 16) | ((b.i + 0x8000u) & 0xFFFF0000u);
}

__device__ __forceinline__ float fexp2(float x) {
#if __has_builtin(__builtin_amdgcn_exp2f)
    return __builtin_amdgcn_exp2f(x);
#else
    return exp2f(x);
#endif
}

__device__ __forceinline__ f32x4 pv_mfma(bf16x4 a, bf16x4 b, f32x4 c) {
#if __has_builtin(__builtin_amdgcn_mfma_f32_16x16x16bf16_1k)
    return __builtin_amdgcn_mfma_f32_16x16x16bf16_1k(a, b, c, 0, 0, 0);
#else
    f32x4 d;
    asm volatile("s_nop 1\n\t"
                 "v_mfma_f32_16x16x16_bf16 %0, %1, %2, %3\n\t"
                 "s_nop 7\n\t"
                 "s_nop 7"
                 : "=v"(d) : "v"(a), "v"(b), "v"(c));
    return d;
#endif
}

// async global->LDS, 16B per lane. LDS dest = wave-uniform base + lane*16.
__device__ __forceinline__ void gl_lds16(const u16* g, u16* l) {
#if __has_builtin(__builtin_amdgcn_global_load_lds)
    __builtin_amdgcn_global_load_lds(
        (const __attribute__((address_space(1))) void*)g,
        (__attribute__((address_space(3))) void*)l, 16, 0, 0);
#else
    *(uint4*)(l + (threadIdx.x & 63) * 8) = *(const uint4*)(g);
#endif
}

// f32 -> bf16 elementwise (fallback path only)
__global__ __launch_bounds__(256) void cvt_kernel(const float* __restrict__ src,
                                                  u16* __restrict__ dst, int n4) {
    int i = blockIdx.x * 256 + threadIdx.x;
    if (i >= n4) return;
    float4 v = ((const float4*)src)[i];
    ushort4 o = { f2bf(v.x), f2bf(v.y), f2bf(v.z), f2bf(v.w) };
    ((ushort4*)dst)[i] = o;
}

// fused prep: convert Wq,Wk,Wv (blocks 0..3071), build mask floats
// (3072..3103), and (full path) convert Q,K,V inputs (3104..27679).
// Fallback path launches only 3104 blocks (qxb/kxb/vxb may be null).
__global__ __launch_bounds__(256) void prep_kernel(
    const float* __restrict__ Wq, const float* __restrict__ Wk,
    const float* __restrict__ Wv, const int* __restrict__ mask,
    const float* __restrict__ Q, const float* __restrict__ K,
    const float* __restrict__ V,
    u16* __restrict__ wqb, u16* __restrict__ wkb, u16* __restrict__ wvb,
    float* __restrict__ mf,
    u16* __restrict__ qxb, u16* __restrict__ kxb, u16* __restrict__ vxb) {
    const int bid = blockIdx.x;
    if (bid < 3072) {
        const float* src = (bid < 1024) ? Wq : (bid < 2048) ? Wk : Wv;
        u16* dst = (bid < 1024) ? wqb : (bid < 2048) ? wkb : wvb;
        int i = (bid & 1023) * 256 + threadIdx.x;
        float4 v = ((const float4*)src)[i];
        ushort4 o = { f2bf(v.x), f2bf(v.y), f2bf(v.z), f2bf(v.w) };
        ((ushort4*)dst)[i] = o;
    } else if (bid < 3104) {
        int i = (bid - 3072) * 256 + threadIdx.x;   // 32 blocks * 256 = 8192
        mf[i] = mask[i] ? 0.0f : NEG2;
    } else {
        const int r = bid - 3104;                   // 0..24575
        const float* src = (r < 8192) ? Q : (r < 16384) ? K : V;
        u16* dst = (r < 8192) ? qxb : (r < 16384) ? kxb : vxb;
        int i = (r & 8191) * 256 + threadIdx.x;
        float4 v = ((const float4*)src)[i];
        ushort4 o = { f2bf(v.x), f2bf(v.y), f2bf(v.z), f2bf(v.w) };
        ((ushort4*)dst)[i] = o;
    }
}

// MERGED m97-style projection (full path): grid (8,192) = 1536 blocks =
// 6 blocks/CU of work, BK=32, 32KB LDS dbuf -> 4 resident blocks/CU.
// FROZEN since round 7 (~85us, ~600 TF).
__global__ __launch_bounds__(256, 4) void projm_kernel(
    const u16* __restrict__ qxb, const u16* __restrict__ kxb,
    const u16* __restrict__ vxb,
    const u16* __restrict__ wqb, const u16* __restrict__ wkb,
    const u16* __restrict__ wvb,
    const float* __restrict__ bq, const float* __restrict__ bv,
    u16* __restrict__ qo, u16* __restrict__ ko, u16* __restrict__ vo)
{
    __shared__ __align__(16) u16 sbuf[2][8192];   // [A 128x32 | B 128x32] = 16KB/buf
    const int p   = blockIdx.y * 8 + blockIdx.x;  // physical linear, x fastest
    const int xcd = p & 7;
    const int i8  = p >> 3;                       // 0..191
    const int ly  = xcd * 24 + (i8 >> 3);         // logical m-panel 0..191
    const int lx  = i8 & 7;                       // logical n-tile 0..7

    const int which = ly >> 6;                    // 0=Q 1=K 2=V
    const u16* X  = (which == 0) ? qxb : (which == 1) ? kxb : vxb;
    const u16* W  = (which == 0) ? wqb : (which == 1) ? wkb : wvb;
    const float* bias = (which == 0) ? bq : (which == 2) ? bv : nullptr;
    u16* out = (which == 0) ? qo : (which == 1) ? ko : vo;
    const int vt = (which == 2);

    const int tid  = threadIdx.x;
    const int lane = tid & 63;
    const int wave = tid >> 6;
    const int row  = lane & 15;
    const int quad = lane >> 4;
    const int n0 = lx * 128;
    const int m0 = (ly & 63) * 128;
    const int wm = (wave & 1) * 64;
    const int wn = (wave >> 1) * 64;

    const int r0 = wave * 16 + (lane >> 2);
    const int c0 = (lane & 3) ^ ((r0 >> 1) & 3);
    const u16* xg0 = X + (size_t)(m0 + r0) * DM + c0 * 8;
    const u16* xg1 = xg0 + (size_t)64 * DM;
    const u16* wg0 = W + (size_t)(n0 + r0) * DM + c0 * 8;
    const u16* wg1 = wg0 + (size_t)64 * DM;
    const int la0 = wave * 512;                   // wave-uniform base (u16)

    const int rsw = (quad ^ ((row >> 1) & 3)) * 8;  // read-side swizzle (0-conflict)

#define STAGE(bsel, kt) do {                         \
        u16* ab = &sbuf[bsel][la0];                  \
        gl_lds16(xg0 + (kt), ab);                    \
        gl_lds16(xg1 + (kt), ab + 2048);             \
        gl_lds16(wg0 + (kt), ab + 4096);             \
        gl_lds16(wg1 + (kt), ab + 6144);             \
    } while (0)

    f32x4 acc[4][4] = {};
    STAGE(0, 0);
    for (int ki = 0; ki < 32; ++ki) {
        __syncthreads();                 // vmcnt(0)+lgkm drain: buf[ki&1] complete
        if (ki < 31) STAGE((ki + 1) & 1, (ki + 1) * 32);

        const u16* Ab = sbuf[ki & 1];
        const u16* Bb = Ab + 4096;
        bf16x8 af[4], bfr[4];
#pragma unroll
        for (int i = 0; i < 4; i++)
            af[i] = *(const bf16x8*)(Ab + (wm + i * 16 + row) * 32 + rsw);
#pragma unroll
        for (int j = 0; j < 4; j++)
            bfr[j] = *(const bf16x8*)(Bb + (wn + j * 16 + row) * 32 + rsw);
#pragma unroll
        for (int i = 0; i < 4; i++)
#pragma unroll
            for (int j = 0; j < 4; j++)
                acc[i][j] = __builtin_amdgcn_mfma_f32_16x16x32_bf16(af[i], bfr[j], acc[i][j], 0, 0, 0);
    }
#undef STAGE

    const int bidx = m0 >> 11;
#pragma unroll
    for (int j = 0; j < 4; j++) {
        const int n = n0 + wn + j * 16 + row;
        const int h = n >> 6;
        const int c = n & (DH - 1);
        const float bvv = bias ? bias[n] : 0.0f;
#pragma unroll
        for (int i = 0; i < 4; i++) {
            const int mbase = m0 + wm + i * 16 + quad * 4;
            const int s = mbase & (SEQ - 1);
            if (vt) {
                ushort4 o = { f2bf(acc[i][j][0] + bvv), f2bf(acc[i][j][1] + bvv),
                              f2bf(acc[i][j][2] + bvv), f2bf(acc[i][j][3] + bvv) };
                size_t idx = (((size_t)(bidx * NH + h) * 32 + (s >> 6)) * DH + c) * 64 + (s & 63);
                *(ushort4*)(out + idx) = o;
            } else {
#pragma unroll
                for (int r = 0; r < 4; r++)
                    out[(size_t)((bidx * NH + h) * SEQ + s + r) * DH + c] = f2bf(acc[i][j][r] + bvv);
            }
        }
    }
}

// Single projection (fallback path, byte-identical to round 6, BK=64).
__global__ __launch_bounds__(256, 2) void proj_kernel(
    const u16* __restrict__ X, const u16* __restrict__ W,
    const float* __restrict__ bias, u16* __restrict__ out, int vt)
{
    __shared__ __align__(16) u16 sbuf[2][16384];
    const int p   = blockIdx.y * 8 + blockIdx.x;
    const int xcd = p & 7;
    const int i8  = p >> 3;                       // 0..63
    const int ly  = xcd * 8 + (i8 >> 3);          // logical m-panel 0..63
    const int lx  = i8 & 7;                       // logical n-tile 0..7

    const int tid  = threadIdx.x;
    const int lane = tid & 63;
    const int wave = tid >> 6;
    const int row  = lane & 15;
    const int quad = lane >> 4;
    const int n0 = lx * 128;
    const int m0 = ly * 128;
    const int wm = (wave & 1) * 64;
    const int wn = (wave >> 1) * 64;

    const int r0 = wave * 16 + (lane >> 2);
    const int c0 = (lane & 3) ^ ((r0 >> 1) & 3);
    const u16* xg0 = X + (size_t)(m0 + r0) * DM + c0 * 8;
    const u16* xg1 = xg0 + (size_t)64 * DM;
    const u16* wg0 = W + (size_t)(n0 + r0) * DM + c0 * 8;
    const u16* wg1 = wg0 + (size_t)64 * DM;
    const int la0 = wave * 512;

    const int rsw = (quad ^ ((row >> 1) & 3)) * 8;

#define STAGE(bsel, kt) do {                                 \
        u16* ab = &sbuf[bsel][la0];                          \
        gl_lds16(xg0 + (kt),        ab);                     \
        gl_lds16(xg1 + (kt),        ab + 2048);              \
        gl_lds16(xg0 + (kt) + 32,   ab + 4096);              \
        gl_lds16(xg1 + (kt) + 32,   ab + 6144);              \
        gl_lds16(wg0 + (kt),        ab + 8192);              \
        gl_lds16(wg1 + (kt),        ab + 10240);             \
        gl_lds16(wg0 + (kt) + 32,   ab + 12288);             \
        gl_lds16(wg1 + (kt) + 32,   ab + 14336);             \
    } while (0)

    f32x4 acc[4][4] = {};
    STAGE(0, 0);
    for (int ki = 0; ki < 16; ++ki) {
        __syncthreads();
        if (ki < 15) STAGE((ki + 1) & 1, (ki + 1) * 64);

        const u16* buf = sbuf[ki & 1];
#pragma unroll
        for (int ks = 0; ks < 2; ++ks) {
            const u16* Ab = buf + ks * 4096;
            const u16* Bb = buf + 8192 + ks * 4096;
            bf16x8 af[4], bfr[4];
#pragma unroll
            for (int i = 0; i < 4; i++)
                af[i] = *(const bf16x8*)(Ab + (wm + i * 16 + row) * 32 + rsw);
#pragma unroll
            for (int j = 0; j < 4; j++)
                bfr[j] = *(const bf16x8*)(Bb + (wn + j * 16 + row) * 32 + rsw);
#pragma unroll
            for (int i = 0; i < 4; i++)
#pragma unroll
                for (int j = 0; j < 4; j++)
                    acc[i][j] = __builtin_amdgcn_mfma_f32_16x16x32_bf16(af[i], bfr[j], acc[i][j], 0, 0, 0);
        }
    }
#undef STAGE

    const int bidx = m0 >> 11;
#pragma unroll
    for (int j = 0; j < 4; j++) {
        const int n = n0 + wn + j * 16 + row;
        const int h = n >> 6;
        const int c = n & (DH - 1);
        const float bvv = bias ? bias[n] : 0.0f;
#pragma unroll
        for (int i = 0; i < 4; i++) {
            const int mbase = m0 + wm + i * 16 + quad * 4;
            const int s = mbase & (SEQ - 1);
            if (vt) {
                ushort4 o = { f2bf(acc[i][j][0] + bvv), f2bf(acc[i][j][1] + bvv),
                              f2bf(acc[i][j][2] + bvv), f2bf(acc[i][j][3] + bvv) };
                size_t idx = (((size_t)(bidx * NH + h) * 32 + (s >> 6)) * DH + c) * 64 + (s & 63);
                *(ushort4*)(out + idx) = o;
            } else {
#pragma unroll
                for (int r = 0; r < 4; r++)
                    out[(size_t)((bidx * NH + h) * SEQ + s + r) * DH + c] = f2bf(acc[i][j][r] + bvv);
            }
        }
    }
}

// Flash attention, transposed-S, no online max. Block = 4 waves x 32 q = 128 q.
// ROUND-7-EXACT (best measured: 117.8us, FETCH 25MB). r8's perm-pack +
// deferred-lsum bundle regressed +5us (matched-but-hurt: VALUBusy fell as
// predicted, dur rose — scheduling perturbation; deferral common to both
// attn regressions). FROZEN at this configuration.
__global__ __launch_bounds__(256, 3) void attn_kernel(
    const u16* __restrict__ qws, const u16* __restrict__ kws,
    const u16* __restrict__ vws, const float* __restrict__ maskf,
    float* __restrict__ out)
{
    __shared__ __align__(16) u16 kbuf[2][64 * 72];   // 9216 B each
    __shared__ __align__(16) u16 vbuf[2][64 * 72];   // rows = dh, cols = key
    const int tid  = threadIdx.x;
    const int lane = tid & 63;
    const int wave = tid >> 6;
    const int row  = lane & 15;
    const int quad = lane >> 4;
    const int bid0 = blockIdx.x;
    const int bid  = ((bid0 & 7) << 7) | (bid0 >> 3);   // XCD-chunked, bijective
    const int qb = bid & 15;            // SEQ/128 = 16
    const int h  = (bid >> 4) & (NH - 1);
    const int b  = bid >> 8;
    const int q0 = qb * 128 + wave * 32;

    const u16* qbase = qws + (size_t)(b * NH + h) * SEQ * DH;
    const u16* kbase = kws + (size_t)(b * NH + h) * SEQ * DH;
    const u16* vtb   = vws + (size_t)(b * NH + h) * 32 * (DH * 64); // tile-blocked
    const float* mrow = maskf + b * SEQ;

    const int srow = tid >> 3;          // 0..31
    const int scol = (tid & 7) * 8;
    const u16* kgp = kbase + (size_t)srow * DH + scol;
    const int ldso = srow * 72 + scol;
    const int vldso = ldso;

    bf16x8 qf[2][2];
#pragma unroll
    for (int gi = 0; gi < 2; gi++) {
        qf[gi][0] = *(const bf16x8*)(qbase + (size_t)(q0 + gi * 16 + row) * DH + quad * 8);
        qf[gi][1] = *(const bf16x8*)(qbase + (size_t)(q0 + gi * 16 + row) * DH + 32 + quad * 8);
    }

    f32x4 O[2][4] = {};
    float lrun[2] = {0.0f, 0.0f};

    {
        uint4 k0 = *(const uint4*)(kgp);
        uint4 k1 = *(const uint4*)(kgp + (size_t)32 * DH);
        uint4 v0 = *(const uint4*)(vtb + tid * 8);
        uint4 v1 = *(const uint4*)(vtb + (tid + 256) * 8);
        *(uint4*)(&kbuf[0][ldso])            = k0;
        *(uint4*)(&kbuf[0][32 * 72 + ldso])  = k1;
        *(uint4*)(&vbuf[0][vldso])           = v0;
        *(uint4*)(&vbuf[0][32 * 72 + vldso]) = v1;
    }

    for (int it = 0; it < 32; ++it) {
        const int kt = it * 64;
        __syncthreads();
        float4 mk[4];
#pragma unroll
        for (int g = 0; g < 4; g++)
            mk[g] = *(const float4*)(mrow + kt + g * 16 + quad * 4);
        const int itn = (it == 31) ? 0 : it + 1;
        uint4 kr0 = *(const uint4*)(kgp + (size_t)itn * 64 * DH);
        uint4 kr1 = *(const uint4*)(kgp + (size_t)(itn * 64 + 32) * DH);
        uint4 vr0 = *(const uint4*)(vtb + (size_t)itn * 4096 + tid * 8);
        uint4 vr1 = *(const uint4*)(vtb + (size_t)itn * 4096 + (tid + 256) * 8);

        const u16* kb = kbuf[it & 1];
        f32x4 st[2][4] = {};
#pragma unroll
        for (int g = 0; g < 4; g++) {
#pragma unroll
            for (int ks = 0; ks < 2; ks++) {
                bf16x8 kf = *(const bf16x8*)(kb + (g * 16 + row) * 72 + ks * 32 + quad * 8);
                st[0][g] = __builtin_amdgcn_mfma_f32_16x16x32_bf16(kf, qf[0][ks], st[0][g], 0, 0, 0);
                st[1][g] = __builtin_amdgcn_mfma_f32_16x16x32_bf16(kf, qf[1][ks], st[1][g], 0, 0, 0);
            }
        }

        union { u32 u[2]; bf16x4 v; } pw[2][4];
#pragma unroll
        for (int gi = 0; gi < 2; gi++) {
            float lsum = 0.0f;
#pragma unroll
            for (int g = 0; g < 4; g++) {
                float p0 = fexp2(fmaf(st[gi][g][0], SCL2, mk[g].x));
                float p1 = fexp2(fmaf(st[gi][g][1], SCL2, mk[g].y));
                float p2 = fexp2(fmaf(st[gi][g][2], SCL2, mk[g].z));
                float p3 = fexp2(fmaf(st[gi][g][3], SCL2, mk[g].w));
                lsum += (p0 + p1) + (p2 + p3);
                pw[gi][g].u[0] = packbf(p0, p1);
                pw[gi][g].u[1] = packbf(p2, p3);
            }
            lsum += __shfl_xor(lsum, 16, 64);
            lsum += __shfl_xor(lsum, 32, 64);
            lrun[gi] += lsum;
        }

        const u16* vb = vbuf[it & 1];
#pragma unroll
        for (int dg = 0; dg < 4; dg++) {
#pragma unroll
            for (int g = 0; g < 4; g++) {
                bf16x4 vfrag = *(const bf16x4*)(vb + (dg * 16 + row) * 72 + g * 16 + quad * 4);
                O[0][dg] = pv_mfma(vfrag, pw[0][g].v, O[0][dg]);
                O[1][dg] = pv_mfma(vfrag, pw[1][g].v, O[1][dg]);
            }
        }

        u16* nkb = kbuf[(it + 1) & 1];
        u16* nvb = vbuf[(it + 1) & 1];
        *(uint4*)(nkb + ldso)             = kr0;
        *(uint4*)(nkb + 32 * 72 + ldso)   = kr1;
        *(uint4*)(nvb + vldso)            = vr0;
        *(uint4*)(nvb + 32 * 72 + vldso)  = vr1;
    }

#pragma unroll
    for (int gi = 0; gi < 2; gi++) {
        const float rl = 1.0f / lrun[gi];
        const int q = q0 + gi * 16 + row;
#pragma unroll
        for (int dg = 0; dg < 4; dg++) {
            float4 o4 = { O[gi][dg][0] * rl, O[gi][dg][1] * rl,
                          O[gi][dg][2] * rl, O[gi][dg][3] * rl };
            *(float4*)(out + (size_t)(b * SEQ + q) * (NH * DH) + h * DH + dg * 16 + quad * 4) = o4;
        }
    }
}

extern "C" void kernel_launch(void* const* d_in, const int* in_sizes, int n_in,
                              void* d_out, int out_size, void* d_ws, size_t ws_size,
                              hipStream_t stream) {
    const float* Q    = (const float*)d_in[0];
    const float* K    = (const float*)d_in[1];
    const float* V    = (const float*)d_in[2];
    const int*   mask = (const int*)d_in[3];
    const float* Wq   = (const float*)d_in[4];
    const float* bq   = (const float*)d_in[5];
    const float* Wk   = (const float*)d_in[6];
    const float* Wv   = (const float*)d_in[7];
    const float* bv   = (const float*)d_in[8];
    float* out = (float*)d_out;

    const size_t XN = (size_t)NB * SEQ * DM;     // 8,388,608
    const size_t WN = (size_t)DM * DM;           // 1,048,576
    dim3 blk(256);

    const size_t need_full = (6 * XN + 3 * WN) * 2 + 32768;   // ~102 MiB

    if (ws_size >= need_full) {
        // ---- full path: 3 kernels total ----
        u16* ws   = (u16*)d_ws;
        u16* qxb  = ws;
        u16* kxb  = qxb + XN;
        u16* vxb  = kxb + XN;
        u16* wqb  = vxb + XN;
        u16* wkb  = wqb + WN;
        u16* wvb  = wkb + WN;
        u16* qws  = wvb + WN;
        u16* kws  = qws + XN;
        u16* vws  = kws + XN;
        float* maskf = (float*)(vws + XN);

        prep_kernel<<<3104 + 3 * 8192, blk, 0, stream>>>(
            Wq, Wk, Wv, mask, Q, K, V, wqb, wkb, wvb, maskf, qxb, kxb, vxb);

        projm_kernel<<<dim3(8, 192), blk, 0, stream>>>(
            qxb, kxb, vxb, wqb, wkb, wvb, bq, bv, qws, kws, vws);

        attn_kernel<<<dim3(NB * NH * (SEQ / 128)), blk, 0, stream>>>(
            qws, kws, vws, maskf, out);
    } else {
        // ---- fallback: round-6 sequence (73.5 MB layout) ----
        u16* ws   = (u16*)d_ws;
        u16* xbuf = ws;                           // reused for Q, K, V inputs
        u16* wqb  = ws + XN;
        u16* wkb  = wqb + WN;
        u16* wvb  = wkb + WN;
        u16* qws  = wvb + WN;
        u16* kws  = qws + XN;
        u16* vws  = kws + XN;
        float* maskf = (float*)(vws + XN);

        const int gX = (int)(XN / 4 / 256);      // 8192
        dim3 pgrid(DM / 128, NB * SEQ / 128);    // (8, 64) = 512 blocks

        prep_kernel<<<3104, blk, 0, stream>>>(
            Wq, Wk, Wv, mask, Q, K, V, wqb, wkb, wvb, maskf,
            nullptr, nullptr, nullptr);

        cvt_kernel<<<gX, blk, 0, stream>>>(K, xbuf, (int)(XN / 4));
        proj_kernel<<<pgrid, blk, 0, stream>>>(xbuf, wkb, nullptr, kws, 0);
        cvt_kernel<<<gX, blk, 0, stream>>>(V, xbuf, (int)(XN / 4));
        proj_kernel<<<pgrid, blk, 0, stream>>>(xbuf, wvb, bv, vws, 1);
        cvt_kernel<<<gX, blk, 0, stream>>>(Q, xbuf, (int)(XN / 4));
        proj_kernel<<<pgrid, blk, 0, stream>>>(xbuf, wqb, bq, qws, 0);

        attn_kernel<<<dim3(NB * NH * (SEQ / 128)), blk, 0, stream>>>(
            qws, kws, vws, maskf, out);
    }
}

// Round 10
// 325.007 us; speedup vs baseline: 1.0190x; 1.0068x over previous
//
#include <hip/hip_runtime.h>
#include <stdint.h>
#include <math.h>

#define NH 16
#define DM 1024
#define SEQ 2048
#define DH 64
#define NB 4
// -1e9 premultiplied by log2(e): masked score -> exp2(-1.44e9) == 0
#define NEG2 (-1.4426950408889634e9f)
// (1/8) * log2(e)
#define SCL2 (0.18033688011112042f)

typedef __attribute__((ext_vector_type(8))) short bf16x8;
typedef __attribute__((ext_vector_type(4))) short bf16x4;
typedef __attribute__((ext_vector_type(4))) float f32x4;
typedef unsigned short u16;
typedef uint32_t u32;

__device__ __forceinline__ u16 f2bf(float f) {     // RNE
    union { float f; u32 i; } c; c.f = f;
    u32 r = c.i + 0x7fffu + ((c.i >> 16) & 1u);
    return (u16)(r >> 16);
}
// pack two f32 -> bf16x2 (round-half-up; inputs are exp() results, finite >=0)
__device__ __forceinline__ u32 packbf(float lo, float hi) {
    union { float f; u32 i; } a, b; a.f = lo; b.f = hi;
    return ((a.i + 0x8000u) >> 16) | ((b.i + 0x8000u) & 0xFFFF0000u);
}

__device__ __forceinline__ float fexp2(float x) {
#if __has_builtin(__builtin_amdgcn_exp2f)
    return __builtin_amdgcn_exp2f(x);
#else
    return exp2f(x);
#endif
}

__device__ __forceinline__ f32x4 pv_mfma(bf16x4 a, bf16x4 b, f32x4 c) {
#if __has_builtin(__builtin_amdgcn_mfma_f32_16x16x16bf16_1k)
    return __builtin_amdgcn_mfma_f32_16x16x16bf16_1k(a, b, c, 0, 0, 0);
#else
    f32x4 d;
    asm volatile("s_nop 1\n\t"
                 "v_mfma_f32_16x16x16_bf16 %0, %1, %2, %3\n\t"
                 "s_nop 7\n\t"
                 "s_nop 7"
                 : "=v"(d) : "v"(a), "v"(b), "v"(c));
    return d;
#endif
}

// async global->LDS, 16B per lane. LDS dest = wave-uniform base + lane*16.
__device__ __forceinline__ void gl_lds16(const u16* g, u16* l) {
#if __has_builtin(__builtin_amdgcn_global_load_lds)
    __builtin_amdgcn_global_load_lds(
        (const __attribute__((address_space(1))) void*)g,
        (__attribute__((address_space(3))) void*)l, 16, 0, 0);
#else
    *(uint4*)(l + (threadIdx.x & 63) * 8) = *(const uint4*)(g);
#endif
}

// f32 -> bf16 elementwise (fallback path only)
__global__ __launch_bounds__(256) void cvt_kernel(const float* __restrict__ src,
                                                  u16* __restrict__ dst, int n4) {
    int i = blockIdx.x * 256 + threadIdx.x;
    if (i >= n4) return;
    float4 v = ((const float4*)src)[i];
    ushort4 o = { f2bf(v.x), f2bf(v.y), f2bf(v.z), f2bf(v.w) };
    ((ushort4*)dst)[i] = o;
}

// fused prep: convert Wq,Wk,Wv (blocks 0..3071), build mask floats
// (3072..3103), and (full path) convert Q,K,V inputs (3104..27679).
// Fallback path launches only 3104 blocks (qxb/kxb/vxb may be null).
__global__ __launch_bounds__(256) void prep_kernel(
    const float* __restrict__ Wq, const float* __restrict__ Wk,
    const float* __restrict__ Wv, const int* __restrict__ mask,
    const float* __restrict__ Q, const float* __restrict__ K,
    const float* __restrict__ V,
    u16* __restrict__ wqb, u16* __restrict__ wkb, u16* __restrict__ wvb,
    float* __restrict__ mf,
    u16* __restrict__ qxb, u16* __restrict__ kxb, u16* __restrict__ vxb) {
    const int bid = blockIdx.x;
    if (bid < 3072) {
        const float* src = (bid < 1024) ? Wq : (bid < 2048) ? Wk : Wv;
        u16* dst = (bid < 1024) ? wqb : (bid < 2048) ? wkb : wvb;
        int i = (bid & 1023) * 256 + threadIdx.x;
        float4 v = ((const float4*)src)[i];
        ushort4 o = { f2bf(v.x), f2bf(v.y), f2bf(v.z), f2bf(v.w) };
        ((ushort4*)dst)[i] = o;
    } else if (bid < 3104) {
        int i = (bid - 3072) * 256 + threadIdx.x;   // 32 blocks * 256 = 8192
        mf[i] = mask[i] ? 0.0f : NEG2;
    } else {
        const int r = bid - 3104;                   // 0..24575
        const float* src = (r < 8192) ? Q : (r < 16384) ? K : V;
        u16* dst = (r < 8192) ? qxb : (r < 16384) ? kxb : vxb;
        int i = (r & 8191) * 256 + threadIdx.x;
        float4 v = ((const float4*)src)[i];
        ushort4 o = { f2bf(v.x), f2bf(v.y), f2bf(v.z), f2bf(v.w) };
        ((ushort4*)dst)[i] = o;
    }
}

// MERGED m97-style projection (full path), counted-vmcnt pipeline (T4):
// TRIPLE-buffer LDS (3x16KB=48KB, 3 blocks/CU, 1536 blocks = exactly 2
// residency waves -> zero tail). Per iter: s_waitcnt vmcnt(4) waits ONLY
// the current tile's 4 gl_lds (next tile's 4 stay in flight across the raw
// s_barrier), then stage tile k+2. Race-freedom: barrier at iter k
// guarantees (a) all waves' tile-k writes landed (each waited vmcnt first),
// (b) all waves finished iter k-1 reads of buf[(k-1)%3] — the buffer that
// tile k+2 overwrites. "memory" clobbers order ds_read/gl_lds around waits.
__global__ __launch_bounds__(256, 3) void projm_kernel(
    const u16* __restrict__ qxb, const u16* __restrict__ kxb,
    const u16* __restrict__ vxb,
    const u16* __restrict__ wqb, const u16* __restrict__ wkb,
    const u16* __restrict__ wvb,
    const float* __restrict__ bq, const float* __restrict__ bv,
    u16* __restrict__ qo, u16* __restrict__ ko, u16* __restrict__ vo)
{
    __shared__ __align__(16) u16 sbuf[3][8192];   // [A 128x32 | B 128x32] = 16KB/buf
    const int p   = blockIdx.y * 8 + blockIdx.x;  // physical linear, x fastest
    const int xcd = p & 7;
    const int i8  = p >> 3;                       // 0..191
    const int ly  = xcd * 24 + (i8 >> 3);         // logical m-panel 0..191
    const int lx  = i8 & 7;                       // logical n-tile 0..7

    const int which = ly >> 6;                    // 0=Q 1=K 2=V
    const u16* X  = (which == 0) ? qxb : (which == 1) ? kxb : vxb;
    const u16* W  = (which == 0) ? wqb : (which == 1) ? wkb : wvb;
    const float* bias = (which == 0) ? bq : (which == 2) ? bv : nullptr;
    u16* out = (which == 0) ? qo : (which == 1) ? ko : vo;
    const int vt = (which == 2);

    const int tid  = threadIdx.x;
    const int lane = tid & 63;
    const int wave = tid >> 6;
    const int row  = lane & 15;
    const int quad = lane >> 4;
    const int n0 = lx * 128;
    const int m0 = (ly & 63) * 128;
    const int wm = (wave & 1) * 64;
    const int wn = (wave >> 1) * 64;

    const int r0 = wave * 16 + (lane >> 2);
    const int c0 = (lane & 3) ^ ((r0 >> 1) & 3);
    const u16* xg0 = X + (size_t)(m0 + r0) * DM + c0 * 8;
    const u16* xg1 = xg0 + (size_t)64 * DM;
    const u16* wg0 = W + (size_t)(n0 + r0) * DM + c0 * 8;
    const u16* wg1 = wg0 + (size_t)64 * DM;
    const int la0 = wave * 512;                   // wave-uniform base (u16)

    const int rsw = (quad ^ ((row >> 1) & 3)) * 8;  // read-side swizzle (0-conflict)

#define STAGE(bsel, kt) do {                         \
        u16* ab = &sbuf[bsel][la0];                  \
        gl_lds16(xg0 + (kt), ab);                    \
        gl_lds16(xg1 + (kt), ab + 2048);             \
        gl_lds16(wg0 + (kt), ab + 4096);             \
        gl_lds16(wg1 + (kt), ab + 6144);             \
    } while (0)

    f32x4 acc[4][4] = {};
    STAGE(0, 0);                          // tile 0: 4 loads in flight
    STAGE(1, 32);                         // tile 1: 8 loads in flight
    for (int ki = 0; ki < 32; ++ki) {
        // wait current tile's 4 loads (leave next tile's 4 in flight);
        // last iteration: nothing behind it, drain fully
        if (ki < 31) { asm volatile("s_waitcnt vmcnt(4)" ::: "memory"); }
        else         { asm volatile("s_waitcnt vmcnt(0)" ::: "memory"); }
        __builtin_amdgcn_s_barrier();
        if (ki < 30) STAGE((ki + 2) % 3, (ki + 2) * 32);

        const u16* Ab = sbuf[ki % 3];
        const u16* Bb = Ab + 4096;
        bf16x8 af[4], bfr[4];
#pragma unroll
        for (int i = 0; i < 4; i++)
            af[i] = *(const bf16x8*)(Ab + (wm + i * 16 + row) * 32 + rsw);
#pragma unroll
        for (int j = 0; j < 4; j++)
            bfr[j] = *(const bf16x8*)(Bb + (wn + j * 16 + row) * 32 + rsw);
#pragma unroll
        for (int i = 0; i < 4; i++)
#pragma unroll
            for (int j = 0; j < 4; j++)
                acc[i][j] = __builtin_amdgcn_mfma_f32_16x16x32_bf16(af[i], bfr[j], acc[i][j], 0, 0, 0);
    }
#undef STAGE

    const int bidx = m0 >> 11;
#pragma unroll
    for (int j = 0; j < 4; j++) {
        const int n = n0 + wn + j * 16 + row;
        const int h = n >> 6;
        const int c = n & (DH - 1);
        const float bvv = bias ? bias[n] : 0.0f;
#pragma unroll
        for (int i = 0; i < 4; i++) {
            const int mbase = m0 + wm + i * 16 + quad * 4;
            const int s = mbase & (SEQ - 1);
            if (vt) {
                ushort4 o = { f2bf(acc[i][j][0] + bvv), f2bf(acc[i][j][1] + bvv),
                              f2bf(acc[i][j][2] + bvv), f2bf(acc[i][j][3] + bvv) };
                size_t idx = (((size_t)(bidx * NH + h) * 32 + (s >> 6)) * DH + c) * 64 + (s & 63);
                *(ushort4*)(out + idx) = o;
            } else {
#pragma unroll
                for (int r = 0; r < 4; r++)
                    out[(size_t)((bidx * NH + h) * SEQ + s + r) * DH + c] = f2bf(acc[i][j][r] + bvv);
            }
        }
    }
}

// Single projection (fallback path, byte-identical to round 6, BK=64).
__global__ __launch_bounds__(256, 2) void proj_kernel(
    const u16* __restrict__ X, const u16* __restrict__ W,
    const float* __restrict__ bias, u16* __restrict__ out, int vt)
{
    __shared__ __align__(16) u16 sbuf[2][16384];
    const int p   = blockIdx.y * 8 + blockIdx.x;
    const int xcd = p & 7;
    const int i8  = p >> 3;                       // 0..63
    const int ly  = xcd * 8 + (i8 >> 3);          // logical m-panel 0..63
    const int lx  = i8 & 7;                       // logical n-tile 0..7

    const int tid  = threadIdx.x;
    const int lane = tid & 63;
    const int wave = tid >> 6;
    const int row  = lane & 15;
    const int quad = lane >> 4;
    const int n0 = lx * 128;
    const int m0 = ly * 128;
    const int wm = (wave & 1) * 64;
    const int wn = (wave >> 1) * 64;

    const int r0 = wave * 16 + (lane >> 2);
    const int c0 = (lane & 3) ^ ((r0 >> 1) & 3);
    const u16* xg0 = X + (size_t)(m0 + r0) * DM + c0 * 8;
    const u16* xg1 = xg0 + (size_t)64 * DM;
    const u16* wg0 = W + (size_t)(n0 + r0) * DM + c0 * 8;
    const u16* wg1 = wg0 + (size_t)64 * DM;
    const int la0 = wave * 512;

    const int rsw = (quad ^ ((row >> 1) & 3)) * 8;

#define STAGE(bsel, kt) do {                                 \
        u16* ab = &sbuf[bsel][la0];                          \
        gl_lds16(xg0 + (kt),        ab);                     \
        gl_lds16(xg1 + (kt),        ab + 2048);              \
        gl_lds16(xg0 + (kt) + 32,   ab + 4096);              \
        gl_lds16(xg1 + (kt) + 32,   ab + 6144);              \
        gl_lds16(wg0 + (kt),        ab + 8192);              \
        gl_lds16(wg1 + (kt),        ab + 10240);             \
        gl_lds16(wg0 + (kt) + 32,   ab + 12288);             \
        gl_lds16(wg1 + (kt) + 32,   ab + 14336);             \
    } while (0)

    f32x4 acc[4][4] = {};
    STAGE(0, 0);
    for (int ki = 0; ki < 16; ++ki) {
        __syncthreads();
        if (ki < 15) STAGE((ki + 1) & 1, (ki + 1) * 64);

        const u16* buf = sbuf[ki & 1];
#pragma unroll
        for (int ks = 0; ks < 2; ++ks) {
            const u16* Ab = buf + ks * 4096;
            const u16* Bb = buf + 8192 + ks * 4096;
            bf16x8 af[4], bfr[4];
#pragma unroll
            for (int i = 0; i < 4; i++)
                af[i] = *(const bf16x8*)(Ab + (wm + i * 16 + row) * 32 + rsw);
#pragma unroll
            for (int j = 0; j < 4; j++)
                bfr[j] = *(const bf16x8*)(Bb + (wn + j * 16 + row) * 32 + rsw);
#pragma unroll
            for (int i = 0; i < 4; i++)
#pragma unroll
                for (int j = 0; j < 4; j++)
                    acc[i][j] = __builtin_amdgcn_mfma_f32_16x16x32_bf16(af[i], bfr[j], acc[i][j], 0, 0, 0);
        }
    }
#undef STAGE

    const int bidx = m0 >> 11;
#pragma unroll
    for (int j = 0; j < 4; j++) {
        const int n = n0 + wn + j * 16 + row;
        const int h = n >> 6;
        const int c = n & (DH - 1);
        const float bvv = bias ? bias[n] : 0.0f;
#pragma unroll
        for (int i = 0; i < 4; i++) {
            const int mbase = m0 + wm + i * 16 + quad * 4;
            const int s = mbase & (SEQ - 1);
            if (vt) {
                ushort4 o = { f2bf(acc[i][j][0] + bvv), f2bf(acc[i][j][1] + bvv),
                              f2bf(acc[i][j][2] + bvv), f2bf(acc[i][j][3] + bvv) };
                size_t idx = (((size_t)(bidx * NH + h) * 32 + (s >> 6)) * DH + c) * 64 + (s & 63);
                *(ushort4*)(out + idx) = o;
            } else {
#pragma unroll
                for (int r = 0; r < 4; r++)
                    out[(size_t)((bidx * NH + h) * SEQ + s + r) * DH + c] = f2bf(acc[i][j][r] + bvv);
            }
        }
    }
}

// Flash attention, transposed-S, no online max. Block = 4 waves x 32 q = 128 q.
// ROUND-7-EXACT (best measured: 117.1-118.0us, FETCH 25MB). FROZEN.
__global__ __launch_bounds__(256, 3) void attn_kernel(
    const u16* __restrict__ qws, const u16* __restrict__ kws,
    const u16* __restrict__ vws, const float* __restrict__ maskf,
    float* __restrict__ out)
{
    __shared__ __align__(16) u16 kbuf[2][64 * 72];   // 9216 B each
    __shared__ __align__(16) u16 vbuf[2][64 * 72];   // rows = dh, cols = key
    const int tid  = threadIdx.x;
    const int lane = tid & 63;
    const int wave = tid >> 6;
    const int row  = lane & 15;
    const int quad = lane >> 4;
    const int bid0 = blockIdx.x;
    const int bid  = ((bid0 & 7) << 7) | (bid0 >> 3);   // XCD-chunked, bijective
    const int qb = bid & 15;            // SEQ/128 = 16
    const int h  = (bid >> 4) & (NH - 1);
    const int b  = bid >> 8;
    const int q0 = qb * 128 + wave * 32;

    const u16* qbase = qws + (size_t)(b * NH + h) * SEQ * DH;
    const u16* kbase = kws + (size_t)(b * NH + h) * SEQ * DH;
    const u16* vtb   = vws + (size_t)(b * NH + h) * 32 * (DH * 64); // tile-blocked
    const float* mrow = maskf + b * SEQ;

    const int srow = tid >> 3;          // 0..31
    const int scol = (tid & 7) * 8;
    const u16* kgp = kbase + (size_t)srow * DH + scol;
    const int ldso = srow * 72 + scol;
    const int vldso = ldso;

    bf16x8 qf[2][2];
#pragma unroll
    for (int gi = 0; gi < 2; gi++) {
        qf[gi][0] = *(const bf16x8*)(qbase + (size_t)(q0 + gi * 16 + row) * DH + quad * 8);
        qf[gi][1] = *(const bf16x8*)(qbase + (size_t)(q0 + gi * 16 + row) * DH + 32 + quad * 8);
    }

    f32x4 O[2][4] = {};
    float lrun[2] = {0.0f, 0.0f};

    {
        uint4 k0 = *(const uint4*)(kgp);
        uint4 k1 = *(const uint4*)(kgp + (size_t)32 * DH);
        uint4 v0 = *(const uint4*)(vtb + tid * 8);
        uint4 v1 = *(const uint4*)(vtb + (tid + 256) * 8);
        *(uint4*)(&kbuf[0][ldso])            = k0;
        *(uint4*)(&kbuf[0][32 * 72 + ldso])  = k1;
        *(uint4*)(&vbuf[0][vldso])           = v0;
        *(uint4*)(&vbuf[0][32 * 72 + vldso]) = v1;
    }

    for (int it = 0; it < 32; ++it) {
        const int kt = it * 64;
        __syncthreads();
        float4 mk[4];
#pragma unroll
        for (int g = 0; g < 4; g++)
            mk[g] = *(const float4*)(mrow + kt + g * 16 + quad * 4);
        const int itn = (it == 31) ? 0 : it + 1;
        uint4 kr0 = *(const uint4*)(kgp + (size_t)itn * 64 * DH);
        uint4 kr1 = *(const uint4*)(kgp + (size_t)(itn * 64 + 32) * DH);
        uint4 vr0 = *(const uint4*)(vtb + (size_t)itn * 4096 + tid * 8);
        uint4 vr1 = *(const uint4*)(vtb + (size_t)itn * 4096 + (tid + 256) * 8);

        const u16* kb = kbuf[it & 1];
        f32x4 st[2][4] = {};
#pragma unroll
        for (int g = 0; g < 4; g++) {
#pragma unroll
            for (int ks = 0; ks < 2; ks++) {
                bf16x8 kf = *(const bf16x8*)(kb + (g * 16 + row) * 72 + ks * 32 + quad * 8);
                st[0][g] = __builtin_amdgcn_mfma_f32_16x16x32_bf16(kf, qf[0][ks], st[0][g], 0, 0, 0);
                st[1][g] = __builtin_amdgcn_mfma_f32_16x16x32_bf16(kf, qf[1][ks], st[1][g], 0, 0, 0);
            }
        }

        union { u32 u[2]; bf16x4 v; } pw[2][4];
#pragma unroll
        for (int gi = 0; gi < 2; gi++) {
            float lsum = 0.0f;
#pragma unroll
            for (int g = 0; g < 4; g++) {
                float p0 = fexp2(fmaf(st[gi][g][0], SCL2, mk[g].x));
                float p1 = fexp2(fmaf(st[gi][g][1], SCL2, mk[g].y));
                float p2 = fexp2(fmaf(st[gi][g][2], SCL2, mk[g].z));
                float p3 = fexp2(fmaf(st[gi][g][3], SCL2, mk[g].w));
                lsum += (p0 + p1) + (p2 + p3);
                pw[gi][g].u[0] = packbf(p0, p1);
                pw[gi][g].u[1] = packbf(p2, p3);
            }
            lsum += __shfl_xor(lsum, 16, 64);
            lsum += __shfl_xor(lsum, 32, 64);
            lrun[gi] += lsum;
        }

        const u16* vb = vbuf[it & 1];
#pragma unroll
        for (int dg = 0; dg < 4; dg++) {
#pragma unroll
            for (int g = 0; g < 4; g++) {
                bf16x4 vfrag = *(const bf16x4*)(vb + (dg * 16 + row) * 72 + g * 16 + quad * 4);
                O[0][dg] = pv_mfma(vfrag, pw[0][g].v, O[0][dg]);
                O[1][dg] = pv_mfma(vfrag, pw[1][g].v, O[1][dg]);
            }
        }

        u16* nkb = kbuf[(it + 1) & 1];
        u16* nvb = vbuf[(it + 1) & 1];
        *(uint4*)(nkb + ldso)             = kr0;
        *(uint4*)(nkb + 32 * 72 + ldso)   = kr1;
        *(uint4*)(nvb + vldso)            = vr0;
        *(uint4*)(nvb + 32 * 72 + vldso)  = vr1;
    }

#pragma unroll
    for (int gi = 0; gi < 2; gi++) {
        const float rl = 1.0f / lrun[gi];
        const int q = q0 + gi * 16 + row;
#pragma unroll
        for (int dg = 0; dg < 4; dg++) {
            float4 o4 = { O[gi][dg][0] * rl, O[gi][dg][1] * rl,
                          O[gi][dg][2] * rl, O[gi][dg][3] * rl };
            *(float4*)(out + (size_t)(b * SEQ + q) * (NH * DH) + h * DH + dg * 16 + quad * 4) = o4;
        }
    }
}

extern "C" void kernel_launch(void* const* d_in, const int* in_sizes, int n_in,
                              void* d_out, int out_size, void* d_ws, size_t ws_size,
                              hipStream_t stream) {
    const float* Q    = (const float*)d_in[0];
    const float* K    = (const float*)d_in[1];
    const float* V    = (const float*)d_in[2];
    const int*   mask = (const int*)d_in[3];
    const float* Wq   = (const float*)d_in[4];
    const float* bq   = (const float*)d_in[5];
    const float* Wk   = (const float*)d_in[6];
    const float* Wv   = (const float*)d_in[7];
    const float* bv   = (const float*)d_in[8];
    float* out = (float*)d_out;

    const size_t XN = (size_t)NB * SEQ * DM;     // 8,388,608
    const size_t WN = (size_t)DM * DM;           // 1,048,576
    dim3 blk(256);

    const size_t need_full = (6 * XN + 3 * WN) * 2 + 32768;   // ~102 MiB

    if (ws_size >= need_full) {
        // ---- full path: 3 kernels total ----
        u16* ws   = (u16*)d_ws;
        u16* qxb  = ws;
        u16* kxb  = qxb + XN;
        u16* vxb  = kxb + XN;
        u16* wqb  = vxb + XN;
        u16* wkb  = wqb + WN;
        u16* wvb  = wkb + WN;
        u16* qws  = wvb + WN;
        u16* kws  = qws + XN;
        u16* vws  = kws + XN;
        float* maskf = (float*)(vws + XN);

        prep_kernel<<<3104 + 3 * 8192, blk, 0, stream>>>(
            Wq, Wk, Wv, mask, Q, K, V, wqb, wkb, wvb, maskf, qxb, kxb, vxb);

        projm_kernel<<<dim3(8, 192), blk, 0, stream>>>(
            qxb, kxb, vxb, wqb, wkb, wvb, bq, bv, qws, kws, vws);

        attn_kernel<<<dim3(NB * NH * (SEQ / 128)), blk, 0, stream>>>(
            qws, kws, vws, maskf, out);
    } else {
        // ---- fallback: round-6 sequence (73.5 MB layout) ----
        u16* ws   = (u16*)d_ws;
        u16* xbuf = ws;                           // reused for Q, K, V inputs
        u16* wqb  = ws + XN;
        u16* wkb  = wqb + WN;
        u16* wvb  = wkb + WN;
        u16* qws  = wvb + WN;
        u16* kws  = qws + XN;
        u16* vws  = kws + XN;
        float* maskf = (float*)(vws + XN);

        const int gX = (int)(XN / 4 / 256);      // 8192
        dim3 pgrid(DM / 128, NB * SEQ / 128);    // (8, 64) = 512 blocks

        prep_kernel<<<3104, blk, 0, stream>>>(
            Wq, Wk, Wv, mask, Q, K, V, wqb, wkb, wvb, maskf,
            nullptr, nullptr, nullptr);

        cvt_kernel<<<gX, blk, 0, stream>>>(K, xbuf, (int)(XN / 4));
        proj_kernel<<<pgrid, blk, 0, stream>>>(xbuf, wkb, nullptr, kws, 0);
        cvt_kernel<<<gX, blk, 0, stream>>>(V, xbuf, (int)(XN / 4));
        proj_kernel<<<pgrid, blk, 0, stream>>>(xbuf, wvb, bv, vws, 1);
        cvt_kernel<<<gX, blk, 0, stream>>>(Q, xbuf, (int)(XN / 4));
        proj_kernel<<<pgrid, blk, 0, stream>>>(xbuf, wqb, bq, qws, 0);

        attn_kernel<<<dim3(NB * NH * (SEQ / 128)), blk, 0, stream>>>(
            qws, kws, vws, maskf, out);
    }
}